// Round 5
// baseline (81.112 us; speedup 1.0000x reference)
//
#include <hip/hip_runtime.h>

// Shape fixed by reference setup_inputs(): B=256, L=512, D=64, fp32.
constexpr int Bn = 256;
constexpr int Ln = 512;
constexpr int Dn = 64;
constexpr float EPS_LOG = 1e-7f;
constexpr float EPS_COS = 1e-8f;

// Reference only consumes wnl[b,b] (the diagonal), so per sample we need just
// one cosine row: cos(emb[b,b,:], emb[b,k,:]) for k in [0,512).
//
// Single fused kernel: one block per sample (grid=256 -> 1 block/CU),
// 1024 threads = 16 waves. Each 16-lane subgroup owns one row k; lane i holds
// float4 emb[b][k][4i..]; a wave's 4 subgroups = 4 consecutive rows = one
// contiguous 1 KB burst; 8 unrolled independent iterations keep 8 KB of loads
// in flight per wave.
//
// Cross-block combine without a second dispatch:
//   - block publishes its contribution via atomicExch(ws+b, contrib)
//     (device-scope store straight to the coherence point; works regardless
//     of ws's poisoned initial contents, no fence needed),
//   - a data-dependency on the exch's return value orders it before the
//     ticket atomicAdd (cheaper than __threadfence's cross-XCD L2 writeback),
//   - the 256th ticket holder reads all partials back with atomicAdd(+0.0f)
//     (device-coherent reads) and writes out[0].
// ws layout (floats): [0..255] per-sample contrib; [256] ticket counter
// (zeroed by a 4-byte memset before launch).
__global__ __launch_bounds__(1024) void wnl_fused(
    const float* __restrict__ emb,     // (B, L, D)
    const float* __restrict__ probs,   // (B, L)
    const float* __restrict__ labels,  // (B, L)
    float* __restrict__ ws,
    float* __restrict__ out)
{
    const int b    = blockIdx.x;
    const int tid  = threadIdx.x;
    const int wave = tid >> 6;         // 0..15
    const int lane = tid & 63;
    const int sub  = lane >> 4;        // row within the wave's 4-row group
    const int i16  = lane & 15;        // float4 chunk of D
    constexpr int NW = 16;

    const float* eb = emb    + (size_t)b * Ln * Dn;
    const float* pb = probs  + (size_t)b * Ln;
    const float* lb = labels + (size_t)b * Ln;

    // prob-sum part: waves 0..7 cover all 512 elements; issue loads early so
    // their latency hides under the row sweep.
    float pos = 0.f, lng = 0.f;
    if (wave < 8) {
        float p   = pb[tid] + EPS_LOG;
        float lab = lb[tid];
        pos = lab * __logf(p);
        lng = __logf(1.f - p);
    }

    // q = emb[b, b, :] (b < 256 <= L); 16 B per lane, broadcast across subgroups
    const float4 qv = *(const float4*)(eb + (size_t)b * Dn + 4 * i16);
    float nq = qv.x * qv.x + qv.y * qv.y + qv.z * qv.z + qv.w * qv.w;
    #pragma unroll
    for (int off = 1; off < 16; off <<= 1) nq += __shfl_xor(nq, off);
    const float norm_q = sqrtf(nq);

    // 512 rows / (16 waves * 4 rows) = 8 unrolled iterations
    float maxv = 0.f;
    #pragma unroll
    for (int it = 0; it < Ln / (NW * 4); ++it) {
        const int k = it * (NW * 4) + wave * 4 + sub;
        const float4 v = *(const float4*)(eb + (size_t)k * Dn + 4 * i16);
        const float lk = lb[k];        // 4 addrs/wave -> one 16 B transaction
        float d = qv.x * v.x + qv.y * v.y + qv.z * v.z + qv.w * v.w;
        float n = v.x * v.x + v.y * v.y + v.z * v.z + v.w * v.w;
        #pragma unroll
        for (int off = 1; off < 16; off <<= 1) {
            d += __shfl_xor(d, off);
            n += __shfl_xor(n, off);
        }
        float denom = fmaxf(norm_q * sqrtf(n), EPS_COS);
        float m     = fmaxf(__fdividef(d, denom), 0.f) * lk;  // relu, mask
        maxv = fmaxf(maxv, m);
    }
    maxv = fmaxf(maxv, __shfl_xor(maxv, 16));
    maxv = fmaxf(maxv, __shfl_xor(maxv, 32));

    if (wave < 8) {
        #pragma unroll
        for (int off = 32; off; off >>= 1) {
            pos += __shfl_xor(pos, off);
            lng += __shfl_xor(lng, off);
        }
    }

    __shared__ float s_max[NW], s_pos[8], s_lng[8];
    __shared__ int s_win;
    if (lane == 0) {
        s_max[wave] = maxv;
        if (wave < 8) { s_pos[wave] = pos; s_lng[wave] = lng; }
    }
    __syncthreads();

    if (tid == 0) {
        float rm = 0.f, P = 0.f, LN = 0.f;
        #pragma unroll
        for (int w = 0; w < NW; ++w) rm = fmaxf(rm, s_max[w]);
        #pragma unroll
        for (int w = 0; w < 8; ++w) { P += s_pos[w]; LN += s_lng[w]; }
        float wnl     = (lb[b] == 0.f) ? rm : 0.f;   // gate on labels[b,b]
        float contrib = -P - wnl * LN;

        // device-scope publish; return value forces completion ordering
        float oldv = atomicExch(ws + b, contrib);
        unsigned inc = 1u | (__float_as_uint(oldv) & 0u);  // == 1, dep on oldv
        unsigned old = atomicAdd((unsigned*)(ws + Bn), inc);
        s_win = (old == (unsigned)(Bn - 1));
    }
    __syncthreads();

    // last-arriving block reduces all 256 partials and writes the scalar
    if (s_win && wave == 0) {
        float t = 0.f;
        #pragma unroll
        for (int j = 0; j < 4; ++j)
            t += atomicAdd(ws + 4 * lane + j, 0.0f);  // coherent read
        #pragma unroll
        for (int off = 32; off; off >>= 1) t += __shfl_xor(t, off);
        if (lane == 0) out[0] = t * (1.f / (float)Bn);
    }
}

extern "C" void kernel_launch(void* const* d_in, const int* in_sizes, int n_in,
                              void* d_out, int out_size, void* d_ws, size_t ws_size,
                              hipStream_t stream) {
    const float* emb    = (const float*)d_in[0];
    const float* probs  = (const float*)d_in[1];
    const float* labels = (const float*)d_in[2];
    float* ws  = (float*)d_ws;
    float* out = (float*)d_out;

    // zero only the 4-byte ticket counter (ws is poisoned 0xAA every launch)
    hipMemsetAsync(ws + Bn, 0, sizeof(unsigned), stream);
    wnl_fused<<<Bn, 1024, 0, stream>>>(emb, probs, labels, ws, out);
}

// Round 6
// 78.441 us; speedup vs baseline: 1.0341x; 1.0341x over previous
//
#include <hip/hip_runtime.h>

// Shape fixed by reference setup_inputs(): B=256, L=512, D=64, fp32.
constexpr int Bn = 256;
constexpr int Ln = 512;
constexpr int Dn = 64;
constexpr int HALF = Ln / 2;       // 256 rows per partial block
constexpr float EPS_LOG = 1e-7f;
constexpr float EPS_COS = 1e-8f;

// Reference only consumes wnl[b,b] (the diagonal), so per sample we need just
// one cosine row: cos(emb[b,b,:], emb[b,k,:]) for k in [0,512).
//
// K1: grid = 512 = 2 blocks per sample (one half of the k-range each) ->
// 2 blocks/CU = 8 waves/SIMD (vs 4 at grid=256) for better cold-start latency
// hiding. 1024 threads = 16 waves. Each 8-lane subgroup owns one row k; lane
// holds 32 B (two float4) of the row, so a wave covers 8 consecutive rows =
// 2 KB contiguous per iteration, 2 iterations per block. 8-lane reduce = 3
// shuffle levels (vs 4 at 16 lanes); total cross-lane ops/wave ~15 (vs ~66 in
// the R4 layout). Results leave via PLAIN stores to distinct addresses (the
// R5 lesson: any same-address atomic rendezvous costs more than a tiny
// second dispatch).
//
// ws layout (floats): [g]       gated half-max   (g = 2b+h, g in [0,512))
//                     [512+g]   half LN = sum log(1-(p+eps))
//                     [1024+g]  half P  = sum labels*log(p+eps)
// Poisoned ws is never read before being overwritten -> no memset dispatch.
__global__ __launch_bounds__(1024, 8) void wnl_part(
    const float* __restrict__ emb,     // (B, L, D)
    const float* __restrict__ probs,   // (B, L)
    const float* __restrict__ labels,  // (B, L)
    float* __restrict__ ws)
{
    const int g    = blockIdx.x;       // 0..511
    const int b    = g >> 1;           // sample
    const int h    = g & 1;            // half of the k-range
    const int tid  = threadIdx.x;
    const int wave = tid >> 6;         // 0..15
    const int lane = tid & 63;
    const int sub  = lane >> 3;        // 0..7 : row within the wave's group
    const int j8   = lane & 7;         // 0..7 : which 32 B chunk of D
    constexpr int NW = 16;

    const float* eb = emb    + (size_t)b * Ln * Dn;
    const float* pb = probs  + (size_t)b * Ln;
    const float* lb = labels + (size_t)b * Ln;

    // prob sums for this half (256 elements -> tids 0..255); issue early so
    // the log latency hides under the row sweep.
    float pos = 0.f, lng = 0.f;
    if (tid < HALF) {
        const int l = h * HALF + tid;
        float p   = pb[l] + EPS_LOG;
        float lab = lb[l];
        pos = lab * __logf(p);
        lng = __logf(1.f - p);
    }

    // q = emb[b, b, :] (b < 256 <= L); lane's 32 B chunk (broadcast across subs)
    const float* qp = eb + (size_t)b * Dn + 8 * j8;
    const float4 qa = *(const float4*)(qp);
    const float4 qb = *(const float4*)(qp + 4);
    float nq = qa.x*qa.x + qa.y*qa.y + qa.z*qa.z + qa.w*qa.w
             + qb.x*qb.x + qb.y*qb.y + qb.z*qb.z + qb.w*qb.w;
    #pragma unroll
    for (int off = 1; off < 8; off <<= 1) nq += __shfl_xor(nq, off);
    const float norm_q = sqrtf(nq);

    // 256 rows / (16 waves * 8 rows) = 2 unrolled iterations
    float maxv = 0.f;
    #pragma unroll
    for (int it = 0; it < HALF / (NW * 8); ++it) {
        const int k = h * HALF + it * (NW * 8) + wave * 8 + sub;
        const float* vp = eb + (size_t)k * Dn + 8 * j8;
        const float4 va = *(const float4*)(vp);
        const float4 vb = *(const float4*)(vp + 4);
        const float lk = lb[k];        // 8 addrs/wave -> one 32 B transaction
        float d = qa.x*va.x + qa.y*va.y + qa.z*va.z + qa.w*va.w
                + qb.x*vb.x + qb.y*vb.y + qb.z*vb.z + qb.w*vb.w;
        float n = va.x*va.x + va.y*va.y + va.z*va.z + va.w*va.w
                + vb.x*vb.x + vb.y*vb.y + vb.z*vb.z + vb.w*vb.w;
        #pragma unroll
        for (int off = 1; off < 8; off <<= 1) {
            d += __shfl_xor(d, off);
            n += __shfl_xor(n, off);
        }
        float denom = fmaxf(norm_q * sqrtf(n), EPS_COS);
        float m     = fmaxf(__fdividef(d, denom), 0.f) * lk;  // relu, mask
        maxv = fmaxf(maxv, m);
    }
    // combine the 8 subgroups' maxima across the wave
    #pragma unroll
    for (int off = 8; off < 64; off <<= 1) maxv = fmaxf(maxv, __shfl_xor(maxv, off));

    // wave-reduce the prob partials (only waves 0..3 hold nonzero)
    if (wave < 4) {
        #pragma unroll
        for (int off = 32; off; off >>= 1) {
            pos += __shfl_xor(pos, off);
            lng += __shfl_xor(lng, off);
        }
    }

    __shared__ float s_max[NW], s_pos[4], s_lng[4];
    if (lane == 0) {
        s_max[wave] = maxv;
        if (wave < 4) { s_pos[wave] = pos; s_lng[wave] = lng; }
    }
    __syncthreads();

    if (tid == 0) {
        float rm = 0.f;
        #pragma unroll
        for (int w = 0; w < NW; ++w) rm = fmaxf(rm, s_max[w]);
        float P  = s_pos[0] + s_pos[1] + s_pos[2] + s_pos[3];
        float LN = s_lng[0] + s_lng[1] + s_lng[2] + s_lng[3];
        // gate on labels[b,b] here (same for both halves)
        ws[g]            = (lb[b] == 0.f) ? rm : 0.f;
        ws[Ln + g]       = LN;
        ws[2 * Ln + g]   = P;
    }
}

// K2: one block of 256 threads combines the 512 half-triples.
__global__ __launch_bounds__(256) void wnl_final(
    const float* __restrict__ ws,
    float* __restrict__ out)
{
    const int b    = threadIdx.x;      // 0..255 = sample
    const int wave = b >> 6, lane = b & 63;

    float m  = fmaxf(ws[2 * b], ws[2 * b + 1]);
    float LN = ws[Ln + 2 * b]     + ws[Ln + 2 * b + 1];
    float P  = ws[2 * Ln + 2 * b] + ws[2 * Ln + 2 * b + 1];
    float t  = -P - m * LN;

    #pragma unroll
    for (int off = 32; off; off >>= 1) t += __shfl_xor(t, off);

    __shared__ float s[4];
    if (lane == 0) s[wave] = t;
    __syncthreads();

    if (b == 0)
        out[0] = (s[0] + s[1] + s[2] + s[3]) * (1.f / (float)Bn);
}

extern "C" void kernel_launch(void* const* d_in, const int* in_sizes, int n_in,
                              void* d_out, int out_size, void* d_ws, size_t ws_size,
                              hipStream_t stream) {
    const float* emb    = (const float*)d_in[0];
    const float* probs  = (const float*)d_in[1];
    const float* labels = (const float*)d_in[2];
    float* ws  = (float*)d_ws;
    float* out = (float*)d_out;

    wnl_part<<<2 * Bn, 1024, 0, stream>>>(emb, probs, labels, ws);
    wnl_final<<<1, 256, 0, stream>>>(ws, out);
}